// Round 1
// baseline (386.009 us; speedup 1.0000x reference)
//
#include <hip/hip_runtime.h>

typedef short short8 __attribute__((ext_vector_type(8)));
typedef float f32x4 __attribute__((ext_vector_type(4)));

#define HDIM 1024
#define TSEQ 2048
#define BATCH 4
#define NH 16
#define HD 64

__device__ __forceinline__ unsigned short f2bf(float f) {
  union { float f; unsigned u; } x; x.f = f;
  unsigned r = x.u + 0x7fffu + ((x.u >> 16) & 1u);
  return (unsigned short)(r >> 16);
}

// 16B-slot XOR swizzle within a 128B row (8 slots)
__device__ __forceinline__ int swz(int row, int slot) { return slot ^ (row & 7); }

// ---------------- weight fp32 -> bf16 ----------------
__global__ __launch_bounds__(256) void convert_w(
    const float* __restrict__ wq, const float* __restrict__ wk,
    const float* __restrict__ wv, const float* __restrict__ wo,
    unsigned short* __restrict__ out) {
  size_t i = ((size_t)blockIdx.x * 256 + threadIdx.x) * 4;   // 4 elems/thread
  int which = (int)(i >> 20);                                // H*H = 2^20
  const float* src = which == 0 ? wq : which == 1 ? wk : which == 2 ? wv : wo;
  size_t off = i & ((1u << 20) - 1);
  float4 v = *reinterpret_cast<const float4*>(src + off);
  unsigned lo = (unsigned)f2bf(v.x) | ((unsigned)f2bf(v.y) << 16);
  unsigned hi = (unsigned)f2bf(v.z) | ((unsigned)f2bf(v.w) << 16);
  uint2 o; o.x = lo; o.y = hi;
  *reinterpret_cast<uint2*>(out + i) = o;
}

// ---------------- LayerNorm -> bf16 ----------------
__global__ __launch_bounds__(256) void ln_kernel(
    const float* __restrict__ x, const float* __restrict__ g,
    const float* __restrict__ bta, unsigned short* __restrict__ h) {
  int row = blockIdx.x;
  int tid = threadIdx.x;
  const float* xr = x + (size_t)row * HDIM;
  float4 v = *reinterpret_cast<const float4*>(xr + tid * 4);
  float s = v.x + v.y + v.z + v.w;
  float sq = v.x * v.x + v.y * v.y + v.z * v.z + v.w * v.w;
  for (int m = 32; m; m >>= 1) { s += __shfl_xor(s, m); sq += __shfl_xor(sq, m); }
  __shared__ float red[8];
  int w = tid >> 6, l = tid & 63;
  if (l == 0) { red[w] = s; red[4 + w] = sq; }
  __syncthreads();
  s = red[0] + red[1] + red[2] + red[3];
  sq = red[4] + red[5] + red[6] + red[7];
  float mu = s * (1.0f / HDIM);
  float var = sq * (1.0f / HDIM) - mu * mu;
  float inv = rsqrtf(var + 1e-5f);
  float4 gv = *reinterpret_cast<const float4*>(g + tid * 4);
  float4 bv = *reinterpret_cast<const float4*>(bta + tid * 4);
  unsigned short o0 = f2bf((v.x - mu) * inv * gv.x + bv.x);
  unsigned short o1 = f2bf((v.y - mu) * inv * gv.y + bv.y);
  unsigned short o2 = f2bf((v.z - mu) * inv * gv.z + bv.z);
  unsigned short o3 = f2bf((v.w - mu) * inv * gv.w + bv.w);
  uint2 o; o.x = (unsigned)o0 | ((unsigned)o1 << 16); o.y = (unsigned)o2 | ((unsigned)o3 << 16);
  *reinterpret_cast<uint2*>(h + (size_t)row * HDIM + tid * 4) = o;
}

// ---------------- GEMM: C = A(bf16 MxK) * W^T(bf16 NxK) + bias ----------------
// MODE 0: QKV -> bf16 out in (B, NH, T, HD) layout, z selects q/k/v
// MODE 1: out-proj -> fp32 out = acc + bias + xres
template <int MODE>
__global__ __launch_bounds__(256) void gemm_k(
    const unsigned short* __restrict__ A, const unsigned short* __restrict__ Wb,
    const float* __restrict__ b0, const float* __restrict__ b1, const float* __restrict__ b2,
    unsigned short* __restrict__ o0, unsigned short* __restrict__ o1, unsigned short* __restrict__ o2,
    const float* __restrict__ xres, float* __restrict__ outf) {
  __shared__ __align__(16) unsigned short Alds[128 * 64];
  __shared__ __align__(16) unsigned short Wlds[128 * 64];
  const int z = blockIdx.z;
  const unsigned short* Wp = Wb + (size_t)z * HDIM * HDIM;
  const float* bias = (z == 0) ? b0 : (z == 1) ? b1 : b2;
  unsigned short* obf = (z == 0) ? o0 : (z == 1) ? o1 : o2;
  const int tid = threadIdx.x;
  const int l = tid & 63, w = tid >> 6;
  const int wr = (w >> 1) * 64, wc = (w & 1) * 64;
  const int bn = blockIdx.x, bm = blockIdx.y;
  const int lrow = l & 15, lk = l >> 4;
  f32x4 acc[4][4] = {};
  for (int kt = 0; kt < 16; ++kt) {
    __syncthreads();
#pragma unroll
    for (int p = 0; p < 4; ++p) {
      int flat = p * 256 + tid;           // 1024 chunks of 16B
      int row = flat >> 3, slot = flat & 7;
      uint4 av = *reinterpret_cast<const uint4*>(A + (size_t)(bm * 128 + row) * HDIM + kt * 64 + slot * 8);
      *reinterpret_cast<uint4*>(reinterpret_cast<char*>(Alds) + row * 128 + swz(row, slot) * 16) = av;
      uint4 wv = *reinterpret_cast<const uint4*>(Wp + (size_t)(bn * 128 + row) * HDIM + kt * 64 + slot * 8);
      *reinterpret_cast<uint4*>(reinterpret_cast<char*>(Wlds) + row * 128 + swz(row, slot) * 16) = wv;
    }
    __syncthreads();
#pragma unroll
    for (int ks = 0; ks < 2; ++ks) {
      short8 af[4], bfr[4];
#pragma unroll
      for (int rt = 0; rt < 4; ++rt) {
        int row = wr + rt * 16 + lrow;
        af[rt] = *reinterpret_cast<const short8*>(reinterpret_cast<char*>(Alds) + row * 128 + swz(row, ks * 4 + lk) * 16);
      }
#pragma unroll
      for (int ct = 0; ct < 4; ++ct) {
        int row = wc + ct * 16 + lrow;
        bfr[ct] = *reinterpret_cast<const short8*>(reinterpret_cast<char*>(Wlds) + row * 128 + swz(row, ks * 4 + lk) * 16);
      }
#pragma unroll
      for (int rt = 0; rt < 4; ++rt)
#pragma unroll
        for (int ct = 0; ct < 4; ++ct)
          acc[rt][ct] = __builtin_amdgcn_mfma_f32_16x16x32_bf16(af[rt], bfr[ct], acc[rt][ct], 0, 0, 0);
    }
  }
#pragma unroll
  for (int rt = 0; rt < 4; ++rt) {
#pragma unroll
    for (int ct = 0; ct < 4; ++ct) {
      int ncol = bn * 128 + wc + ct * 16 + lrow;
      float bv = bias[ncol];
#pragma unroll
      for (int r = 0; r < 4; ++r) {
        int mrow = bm * 128 + wr + rt * 16 + lk * 4 + r;
        float val = acc[rt][ct][r] + bv;
        if (MODE == 0) {
          int bb = mrow >> 11, t = mrow & (TSEQ - 1);
          int head = ncol >> 6, d = ncol & 63;
          obf[((size_t)(bb * NH + head) * TSEQ + t) * HD + d] = f2bf(val);
        } else {
          size_t idx = (size_t)mrow * HDIM + ncol;
          outf[idx] = val + xres[idx];
        }
      }
    }
  }
}

// ---------------- flash attention ----------------
// grid: (T/128, NH, B), block 256 (4 waves, each wave 32 q rows)
__global__ __launch_bounds__(256) void attn_kernel(
    const unsigned short* __restrict__ q_s, const unsigned short* __restrict__ k_s,
    const unsigned short* __restrict__ v_s, const int* __restrict__ mask,
    unsigned short* __restrict__ c) {
  __shared__ __align__(16) unsigned short Klds[64 * 64];
  __shared__ __align__(16) unsigned short Vtlds[64 * 64];
  __shared__ __align__(16) unsigned short Plds[4 * 32 * 64];
  __shared__ int mlds[64];
  const int b = blockIdx.z, head = blockIdx.y, qb = blockIdx.x;
  const unsigned short* qp = q_s + ((size_t)(b * NH + head) * TSEQ + qb * 128) * HD;
  const unsigned short* kp = k_s + (size_t)(b * NH + head) * TSEQ * HD;
  const unsigned short* vp = v_s + (size_t)(b * NH + head) * TSEQ * HD;
  const int tid = threadIdx.x, l = tid & 63, w = tid >> 6;
  const int lrow = l & 15, lk = l >> 4;

  short8 qf[2][2];
#pragma unroll
  for (int rt = 0; rt < 2; ++rt)
#pragma unroll
    for (int ks = 0; ks < 2; ++ks)
      qf[rt][ks] = *reinterpret_cast<const short8*>(qp + (size_t)(w * 32 + rt * 16 + lrow) * HD + ks * 32 + lk * 8);

  f32x4 acc[2][4] = {};
  float mrow_[2][4], lsum[2][4];
#pragma unroll
  for (int rt = 0; rt < 2; ++rt)
#pragma unroll
    for (int r = 0; r < 4; ++r) { mrow_[rt][r] = -1e30f; lsum[rt][r] = 0.0f; }

  for (int kv = 0; kv < TSEQ / 64; ++kv) {
    __syncthreads();
    // stage K (row-major, swizzled) and V^T (transposed, swizzled)
#pragma unroll
    for (int p = 0; p < 2; ++p) {
      int flat = p * 256 + tid;          // 512 chunks of 16B
      int row = flat >> 3, slot = flat & 7;
      uint4 kvv = *reinterpret_cast<const uint4*>(kp + (size_t)(kv * 64 + row) * HD + slot * 8);
      *reinterpret_cast<uint4*>(reinterpret_cast<char*>(Klds) + row * 128 + swz(row, slot) * 16) = kvv;
      union { uint4 u; unsigned short s[8]; } tv;
      tv.u = *reinterpret_cast<const uint4*>(vp + (size_t)(kv * 64 + row) * HD + slot * 8);
#pragma unroll
      for (int j = 0; j < 8; ++j) {
        int d = slot * 8 + j, key = row;
        *reinterpret_cast<unsigned short*>(reinterpret_cast<char*>(Vtlds) + d * 128 + swz(d, key >> 3) * 16 + (key & 7) * 2) = tv.s[j];
      }
    }
    if (tid < 64) mlds[tid] = mask[b * TSEQ + kv * 64 + tid];
    __syncthreads();

    // S = Q K^T
    f32x4 s[2][4] = {};
#pragma unroll
    for (int ks = 0; ks < 2; ++ks) {
      short8 kf[4];
#pragma unroll
      for (int ct = 0; ct < 4; ++ct) {
        int row = ct * 16 + lrow;
        kf[ct] = *reinterpret_cast<const short8*>(reinterpret_cast<char*>(Klds) + row * 128 + swz(row, ks * 4 + lk) * 16);
      }
#pragma unroll
      for (int rt = 0; rt < 2; ++rt)
#pragma unroll
        for (int ct = 0; ct < 4; ++ct)
          s[rt][ct] = __builtin_amdgcn_mfma_f32_16x16x32_bf16(qf[rt][ks], kf[ct], s[rt][ct], 0, 0, 0);
    }

    float mk[4];
#pragma unroll
    for (int ct = 0; ct < 4; ++ct) mk[ct] = mlds[ct * 16 + lrow] ? -1e30f : 0.0f;

#pragma unroll
    for (int rt = 0; rt < 2; ++rt) {
#pragma unroll
      for (int ct = 0; ct < 4; ++ct)
#pragma unroll
        for (int r = 0; r < 4; ++r)
          s[rt][ct][r] = s[rt][ct][r] * 0.125f + mk[ct];
#pragma unroll
      for (int r = 0; r < 4; ++r) {
        float mx = fmaxf(fmaxf(s[rt][0][r], s[rt][1][r]), fmaxf(s[rt][2][r], s[rt][3][r]));
#pragma unroll
        for (int msk = 1; msk < 16; msk <<= 1) mx = fmaxf(mx, __shfl_xor(mx, msk));
        float mnew = fmaxf(mrow_[rt][r], mx);
        float scalef = __expf(mrow_[rt][r] - mnew);
        mrow_[rt][r] = mnew;
        float psum = 0.0f;
#pragma unroll
        for (int ct = 0; ct < 4; ++ct) {
          float p = __expf(s[rt][ct][r] - mnew);
          s[rt][ct][r] = p;
          psum += p;
        }
#pragma unroll
        for (int msk = 1; msk < 16; msk <<= 1) psum += __shfl_xor(psum, msk);
        lsum[rt][r] = lsum[rt][r] * scalef + psum;
#pragma unroll
        for (int ctv = 0; ctv < 4; ++ctv) acc[rt][ctv][r] *= scalef;
      }
      // write P (bf16) to per-wave LDS region
#pragma unroll
      for (int ct = 0; ct < 4; ++ct)
#pragma unroll
        for (int r = 0; r < 4; ++r) {
          int rl = rt * 16 + lk * 4 + r, key = ct * 16 + lrow;
          *reinterpret_cast<unsigned short*>(reinterpret_cast<char*>(Plds) + w * 4096 + rl * 128 + swz(rl, key >> 3) * 16 + (key & 7) * 2) = f2bf(s[rt][ct][r]);
        }
    }

    // O += P V
#pragma unroll
    for (int ks = 0; ks < 2; ++ks) {
      short8 pf[2], vf[4];
#pragma unroll
      for (int rt = 0; rt < 2; ++rt) {
        int rl = rt * 16 + lrow;
        pf[rt] = *reinterpret_cast<const short8*>(reinterpret_cast<char*>(Plds) + w * 4096 + rl * 128 + swz(rl, ks * 4 + lk) * 16);
      }
#pragma unroll
      for (int ctv = 0; ctv < 4; ++ctv) {
        int d = ctv * 16 + lrow;
        vf[ctv] = *reinterpret_cast<const short8*>(reinterpret_cast<char*>(Vtlds) + d * 128 + swz(d, ks * 4 + lk) * 16);
      }
#pragma unroll
      for (int rt = 0; rt < 2; ++rt)
#pragma unroll
        for (int ctv = 0; ctv < 4; ++ctv)
          acc[rt][ctv] = __builtin_amdgcn_mfma_f32_16x16x32_bf16(pf[rt], vf[ctv], acc[rt][ctv], 0, 0, 0);
    }
  }

  // epilogue: O /= l, write c in (B,T,H) bf16
#pragma unroll
  for (int rt = 0; rt < 2; ++rt)
#pragma unroll
    for (int r = 0; r < 4; ++r) {
      float inv = 1.0f / lsum[rt][r];
      int t = qb * 128 + w * 32 + rt * 16 + lk * 4 + r;
#pragma unroll
      for (int ctv = 0; ctv < 4; ++ctv) {
        int col = head * HD + ctv * 16 + lrow;
        c[((size_t)(b * TSEQ) + t) * HDIM + col] = f2bf(acc[rt][ctv][r] * inv);
      }
    }
}

extern "C" void kernel_launch(void* const* d_in, const int* in_sizes, int n_in,
                              void* d_out, int out_size, void* d_ws, size_t ws_size,
                              hipStream_t stream) {
  const float* x   = (const float*)d_in[0];
  const int* mask  = (const int*)d_in[1];
  const float* lng = (const float*)d_in[2];
  const float* lnb = (const float*)d_in[3];
  const float* wq  = (const float*)d_in[4];
  const float* bq  = (const float*)d_in[5];
  const float* wk  = (const float*)d_in[6];
  const float* bk  = (const float*)d_in[7];
  const float* wv  = (const float*)d_in[8];
  const float* bv  = (const float*)d_in[9];
  const float* wo  = (const float*)d_in[10];
  const float* bo  = (const float*)d_in[11];
  float* out = (float*)d_out;
  char* ws = (char*)d_ws;

  unsigned short* h   = (unsigned short*)ws;                       // 16MB (B*T*H bf16)
  unsigned short* wbf = (unsigned short*)(ws + (16u << 20));       // 8MB (4 weights bf16)
  unsigned short* qs  = (unsigned short*)(ws + (24u << 20));       // 16MB
  unsigned short* ks  = (unsigned short*)(ws + (40u << 20));       // 16MB
  unsigned short* vs  = (unsigned short*)(ws + (56u << 20));       // 16MB
  unsigned short* c   = h;  // h dead after QKV GEMM

  convert_w<<<4096, 256, 0, stream>>>(wq, wk, wv, wo, wbf);
  ln_kernel<<<BATCH * TSEQ, 256, 0, stream>>>(x, lng, lnb, h);
  gemm_k<0><<<dim3(8, 64, 3), 256, 0, stream>>>(h, wbf, bq, bk, bv, qs, ks, vs, nullptr, nullptr);
  attn_kernel<<<dim3(TSEQ / 128, NH, BATCH), 256, 0, stream>>>(qs, ks, vs, mask, c);
  gemm_k<1><<<dim3(8, 64, 1), 256, 0, stream>>>(c, wbf + (size_t)3 * HDIM * HDIM, bo, nullptr, nullptr,
                                                nullptr, nullptr, nullptr, x, out);
}

// Round 2
// 310.820 us; speedup vs baseline: 1.2419x; 1.2419x over previous
//
#include <hip/hip_runtime.h>

typedef short short8 __attribute__((ext_vector_type(8)));
typedef float f32x4 __attribute__((ext_vector_type(4)));

#define HDIM 1024
#define TSEQ 2048
#define BATCH 4
#define NH 16
#define HD 64

__device__ __forceinline__ unsigned short f2bf(float f) {
  union { float f; unsigned u; } x; x.f = f;
  unsigned r = x.u + 0x7fffu + ((x.u >> 16) & 1u);
  return (unsigned short)(r >> 16);
}

// 16B-slot XOR swizzle within a 128B row (8 slots)
__device__ __forceinline__ int swz(int row, int slot) { return slot ^ (row & 7); }

// ---------------- weight fp32 -> bf16 ----------------
__global__ __launch_bounds__(256) void convert_w(
    const float* __restrict__ wq, const float* __restrict__ wk,
    const float* __restrict__ wv, const float* __restrict__ wo,
    unsigned short* __restrict__ out) {
  size_t i = ((size_t)blockIdx.x * 256 + threadIdx.x) * 4;   // 4 elems/thread
  int which = (int)(i >> 20);                                // H*H = 2^20
  const float* src = which == 0 ? wq : which == 1 ? wk : which == 2 ? wv : wo;
  size_t off = i & ((1u << 20) - 1);
  float4 v = *reinterpret_cast<const float4*>(src + off);
  unsigned lo = (unsigned)f2bf(v.x) | ((unsigned)f2bf(v.y) << 16);
  unsigned hi = (unsigned)f2bf(v.z) | ((unsigned)f2bf(v.w) << 16);
  uint2 o; o.x = lo; o.y = hi;
  *reinterpret_cast<uint2*>(out + i) = o;
}

// ---------------- LayerNorm -> bf16 ----------------
__global__ __launch_bounds__(256) void ln_kernel(
    const float* __restrict__ x, const float* __restrict__ g,
    const float* __restrict__ bta, unsigned short* __restrict__ h) {
  int row = blockIdx.x;
  int tid = threadIdx.x;
  const float* xr = x + (size_t)row * HDIM;
  float4 v = *reinterpret_cast<const float4*>(xr + tid * 4);
  float s = v.x + v.y + v.z + v.w;
  float sq = v.x * v.x + v.y * v.y + v.z * v.z + v.w * v.w;
  for (int m = 32; m; m >>= 1) { s += __shfl_xor(s, m); sq += __shfl_xor(sq, m); }
  __shared__ float red[8];
  int w = tid >> 6, l = tid & 63;
  if (l == 0) { red[w] = s; red[4 + w] = sq; }
  __syncthreads();
  s = red[0] + red[1] + red[2] + red[3];
  sq = red[4] + red[5] + red[6] + red[7];
  float mu = s * (1.0f / HDIM);
  float var = sq * (1.0f / HDIM) - mu * mu;
  float inv = rsqrtf(var + 1e-5f);
  float4 gv = *reinterpret_cast<const float4*>(g + tid * 4);
  float4 bv = *reinterpret_cast<const float4*>(bta + tid * 4);
  unsigned short o0 = f2bf((v.x - mu) * inv * gv.x + bv.x);
  unsigned short o1 = f2bf((v.y - mu) * inv * gv.y + bv.y);
  unsigned short o2 = f2bf((v.z - mu) * inv * gv.z + bv.z);
  unsigned short o3 = f2bf((v.w - mu) * inv * gv.w + bv.w);
  uint2 o; o.x = (unsigned)o0 | ((unsigned)o1 << 16); o.y = (unsigned)o2 | ((unsigned)o3 << 16);
  *reinterpret_cast<uint2*>(h + (size_t)row * HDIM + tid * 4) = o;
}

// ---------------- GEMM: C = A(bf16 MxK) * W^T(bf16 NxK) + bias ----------------
// MODE 0: QKV -> bf16 out in (B, NH, T, HD) layout, z selects q/k/v (q scaled by 1/8)
// MODE 1: out-proj -> fp32 out = acc + bias + xres
template <int MODE>
__global__ __launch_bounds__(256) void gemm_k(
    const unsigned short* __restrict__ A, const unsigned short* __restrict__ Wb,
    const float* __restrict__ b0, const float* __restrict__ b1, const float* __restrict__ b2,
    unsigned short* __restrict__ o0, unsigned short* __restrict__ o1, unsigned short* __restrict__ o2,
    const float* __restrict__ xres, float* __restrict__ outf) {
  __shared__ __align__(16) unsigned short Alds[128 * 64];
  __shared__ __align__(16) unsigned short Wlds[128 * 64];
  const int z = blockIdx.z;
  const unsigned short* Wp = Wb + (size_t)z * HDIM * HDIM;
  const float* bias = (z == 0) ? b0 : (z == 1) ? b1 : b2;
  unsigned short* obf = (z == 0) ? o0 : (z == 1) ? o1 : o2;
  const int tid = threadIdx.x;
  const int l = tid & 63, w = tid >> 6;
  const int wr = (w >> 1) * 64, wc = (w & 1) * 64;
  const int bn = blockIdx.x, bm = blockIdx.y;
  const int lrow = l & 15, lk = l >> 4;
  f32x4 acc[4][4] = {};
  for (int kt = 0; kt < 16; ++kt) {
    __syncthreads();
#pragma unroll
    for (int p = 0; p < 4; ++p) {
      int flat = p * 256 + tid;           // 1024 chunks of 16B
      int row = flat >> 3, slot = flat & 7;
      uint4 av = *reinterpret_cast<const uint4*>(A + (size_t)(bm * 128 + row) * HDIM + kt * 64 + slot * 8);
      *reinterpret_cast<uint4*>(reinterpret_cast<char*>(Alds) + row * 128 + swz(row, slot) * 16) = av;
      uint4 wv = *reinterpret_cast<const uint4*>(Wp + (size_t)(bn * 128 + row) * HDIM + kt * 64 + slot * 8);
      *reinterpret_cast<uint4*>(reinterpret_cast<char*>(Wlds) + row * 128 + swz(row, slot) * 16) = wv;
    }
    __syncthreads();
#pragma unroll
    for (int ks = 0; ks < 2; ++ks) {
      short8 af[4], bfr[4];
#pragma unroll
      for (int rt = 0; rt < 4; ++rt) {
        int row = wr + rt * 16 + lrow;
        af[rt] = *reinterpret_cast<const short8*>(reinterpret_cast<char*>(Alds) + row * 128 + swz(row, ks * 4 + lk) * 16);
      }
#pragma unroll
      for (int ct = 0; ct < 4; ++ct) {
        int row = wc + ct * 16 + lrow;
        bfr[ct] = *reinterpret_cast<const short8*>(reinterpret_cast<char*>(Wlds) + row * 128 + swz(row, ks * 4 + lk) * 16);
      }
#pragma unroll
      for (int rt = 0; rt < 4; ++rt)
#pragma unroll
        for (int ct = 0; ct < 4; ++ct)
          acc[rt][ct] = __builtin_amdgcn_mfma_f32_16x16x32_bf16(af[rt], bfr[ct], acc[rt][ct], 0, 0, 0);
    }
  }
#pragma unroll
  for (int rt = 0; rt < 4; ++rt) {
#pragma unroll
    for (int ct = 0; ct < 4; ++ct) {
      int ncol = bn * 128 + wc + ct * 16 + lrow;
      float bv = bias[ncol];
#pragma unroll
      for (int r = 0; r < 4; ++r) {
        int mrow = bm * 128 + wr + rt * 16 + lk * 4 + r;
        float val = acc[rt][ct][r] + bv;
        if (MODE == 0) {
          if (z == 0) val *= 0.125f;      // fold 1/sqrt(HEAD) into Q
          int bb = mrow >> 11, t = mrow & (TSEQ - 1);
          int head = ncol >> 6, d = ncol & 63;
          obf[((size_t)(bb * NH + head) * TSEQ + t) * HD + d] = f2bf(val);
        } else {
          size_t idx = (size_t)mrow * HDIM + ncol;
          outf[idx] = val + xres[idx];
        }
      }
    }
  }
}

// ---------------- flash attention, swapped-QK^T ----------------
// grid: (T/128, NH, B), block 256 (4 waves, each wave 32 q rows), KVBLK=64
__global__ __launch_bounds__(256) void attn_kernel(
    const unsigned short* __restrict__ q_s, const unsigned short* __restrict__ k_s,
    const unsigned short* __restrict__ v_s, const int* __restrict__ mask,
    unsigned short* __restrict__ c) {
  __shared__ __align__(16) unsigned short Klds[64 * 64];
  __shared__ __align__(16) unsigned short Vlds[64 * 64];
  __shared__ __align__(16) unsigned short Plds[4][32 * 64];
  __shared__ __align__(16) float mzlds[64];
  __shared__ float slds[4][32];
  const int b = blockIdx.z, head = blockIdx.y, qb = blockIdx.x;
  const unsigned short* qp = q_s + ((size_t)(b * NH + head) * TSEQ + qb * 128) * HD;
  const unsigned short* kp = k_s + (size_t)(b * NH + head) * TSEQ * HD;
  const unsigned short* vp = v_s + (size_t)(b * NH + head) * TSEQ * HD;
  const int tid = threadIdx.x, l = tid & 63, w = tid >> 6;
  const int lrow = l & 15, hi = l >> 4;
  char* Kb = reinterpret_cast<char*>(Klds);
  char* Vb = reinterpret_cast<char*>(Vlds);
  char* Pb = reinterpret_cast<char*>(&Plds[w][0]);
  const int rr = tid >> 3, ss = tid & 7;    // staging coords: rows rr/rr+32, 16B slot ss

  // Q fragments (B-operand): lane holds Q[q = w*32 + qt*16 + lrow][d = ks*32 + hi*8 ..+7]
  short8 qf[2][2];
#pragma unroll
  for (int qt = 0; qt < 2; ++qt)
#pragma unroll
    for (int ks = 0; ks < 2; ++ks)
      qf[qt][ks] = *reinterpret_cast<const short8*>(qp + (size_t)(w * 32 + qt * 16 + lrow) * HD + ks * 32 + hi * 8);

  f32x4 acc[2][4] = {};
  float mreg[2] = {-1e30f, -1e30f};
  float lsum[2] = {0.0f, 0.0f};

  uint4 kpre[2], vpre[2];
  float mpre = 0.0f;

  auto ISSUE = [&](int kv) {
#pragma unroll
    for (int p = 0; p < 2; ++p) {
      int row = p * 32 + rr;
      kpre[p] = *reinterpret_cast<const uint4*>(kp + (size_t)(kv * 64 + row) * HD + ss * 8);
      vpre[p] = *reinterpret_cast<const uint4*>(vp + (size_t)(kv * 64 + row) * HD + ss * 8);
    }
    if (tid < 64) mpre = mask[b * TSEQ + kv * 64 + tid] ? 0.0f : 1.0f;
  };

  ISSUE(0);

  for (int kv = 0; kv < TSEQ / 64; ++kv) {
    __syncthreads();   // all waves done reading previous tile
    // ---- write staged tile to LDS ----
#pragma unroll
    for (int p = 0; p < 2; ++p) {
      int row = p * 32 + rr;
      *reinterpret_cast<uint4*>(Kb + row * 128 + ((ss ^ (row & 7)) << 4)) = kpre[p];
      union { uint4 u; unsigned short s[8]; } tv; tv.u = vpre[p];
#pragma unroll
      for (int j = 0; j < 8; ++j) {
        int d = ss * 8 + j;
        *reinterpret_cast<unsigned short*>(
            Vb + d * 128 + ((((row >> 3) ^ (d & 7) ^ (d >> 3)) & 7) << 4) + ((row & 7) << 1)) = tv.s[j];
      }
    }
    if (tid < 64) mzlds[tid] = mpre;
    if (kv + 1 < TSEQ / 64) ISSUE(kv + 1);   // prefetch next tile (lands during compute)
    __syncthreads();   // tile ready

    // ---- S^T = K Q^T : st[kt][qt], S^T[k = kt*16 + hi*4 + r][q = qt*16 + lrow] ----
    f32x4 st[4][2] = {};
#pragma unroll
    for (int ks = 0; ks < 2; ++ks) {
      short8 kf[4];
#pragma unroll
      for (int kt = 0; kt < 4; ++kt) {
        int row = kt * 16 + lrow;
        kf[kt] = *reinterpret_cast<const short8*>(Kb + row * 128 + (((ks * 4 + hi) ^ (row & 7)) << 4));
      }
#pragma unroll
      for (int kt = 0; kt < 4; ++kt)
#pragma unroll
        for (int qt = 0; qt < 2; ++qt)
          st[kt][qt] = __builtin_amdgcn_mfma_f32_16x16x32_bf16(kf[kt], qf[qt][ks], st[kt][qt], 0, 0, 0);
    }

    // mask multipliers: mz[kt][r] for k = kt*16 + hi*4 + r
    float4 mz[4];
#pragma unroll
    for (int kt = 0; kt < 4; ++kt)
      mz[kt] = *reinterpret_cast<const float4*>(&mzlds[kt * 16 + hi * 4]);

    // ---- online softmax (per lane: q = qt*16 + lrow, 16 k-values in regs) ----
    float scl[2];
#pragma unroll
    for (int qt = 0; qt < 2; ++qt) {
      float mx = st[0][qt][0];
#pragma unroll
      for (int kt = 0; kt < 4; ++kt)
#pragma unroll
        for (int r = 0; r < 4; ++r) mx = fmaxf(mx, st[kt][qt][r]);
      mx = fmaxf(mx, __shfl_xor(mx, 16));
      mx = fmaxf(mx, __shfl_xor(mx, 32));
      float mnew = fmaxf(mreg[qt], mx);
      scl[qt] = __expf(mreg[qt] - mnew);
      mreg[qt] = mnew;
      float ps = 0.0f;
#pragma unroll
      for (int kt = 0; kt < 4; ++kt) {
        float* mzp = reinterpret_cast<float*>(&mz[kt]);
#pragma unroll
        for (int r = 0; r < 4; ++r) {
          float p = __expf(st[kt][qt][r] - mnew) * mzp[r];
          st[kt][qt][r] = p;
          ps += p;
        }
      }
      ps += __shfl_xor(ps, 16);
      ps += __shfl_xor(ps, 32);
      lsum[qt] = lsum[qt] * scl[qt] + ps;
      slds[w][qt * 16 + lrow] = scl[qt];   // broadcast scale to acc layout (wave-local)
    }

    // ---- write P (bf16) to per-wave LDS: row q, swizzled 8B slots ----
#pragma unroll
    for (int qt = 0; qt < 2; ++qt) {
      int q = qt * 16 + lrow;
#pragma unroll
      for (int kt = 0; kt < 4; ++kt) {
        uint2 pw;
        pw.x = (unsigned)f2bf(st[kt][qt][0]) | ((unsigned)f2bf(st[kt][qt][1]) << 16);
        pw.y = (unsigned)f2bf(st[kt][qt][2]) | ((unsigned)f2bf(st[kt][qt][3]) << 16);
        *reinterpret_cast<uint2*>(
            Pb + q * 128 + ((((kt * 2 + (hi >> 1)) ^ (q & 7)) & 7) << 4) + ((hi & 1) << 3)) = pw;
      }
    }

    // ---- rescale acc (acc layout: q = qt*16 + hi*4 + r) ----
#pragma unroll
    for (int qt = 0; qt < 2; ++qt) {
#pragma unroll
      for (int r = 0; r < 4; ++r) {
        float sc = slds[w][qt * 16 + hi * 4 + r];
#pragma unroll
        for (int dc = 0; dc < 4; ++dc) acc[qt][dc][r] *= sc;
      }
    }

    // ---- O += P V ----
#pragma unroll
    for (int ks = 0; ks < 2; ++ks) {
      short8 pa[2], vf[4];
#pragma unroll
      for (int qt = 0; qt < 2; ++qt) {
        int q = qt * 16 + lrow;
        pa[qt] = *reinterpret_cast<const short8*>(Pb + q * 128 + (((ks * 4 + hi) ^ (q & 7)) << 4));
      }
#pragma unroll
      for (int dc = 0; dc < 4; ++dc) {
        int d = dc * 16 + lrow;
        vf[dc] = *reinterpret_cast<const short8*>(
            Vb + d * 128 + ((((ks * 4 + hi) ^ (d & 7) ^ (d >> 3)) & 7) << 4));
      }
#pragma unroll
      for (int qt = 0; qt < 2; ++qt)
#pragma unroll
        for (int dc = 0; dc < 4; ++dc)
          acc[qt][dc] = __builtin_amdgcn_mfma_f32_16x16x32_bf16(pa[qt], vf[dc], acc[qt][dc], 0, 0, 0);
    }
  }

  // ---- epilogue: O /= lsum, write c (B,T,H) bf16 ----
#pragma unroll
  for (int qt = 0; qt < 2; ++qt) slds[w][qt * 16 + lrow] = lsum[qt];
#pragma unroll
  for (int qt = 0; qt < 2; ++qt) {
#pragma unroll
    for (int r = 0; r < 4; ++r) {
      float inv = 1.0f / slds[w][qt * 16 + hi * 4 + r];
      int t = qb * 128 + w * 32 + qt * 16 + hi * 4 + r;
#pragma unroll
      for (int dc = 0; dc < 4; ++dc) {
        int col = head * HD + dc * 16 + lrow;
        c[((size_t)(b * TSEQ) + t) * HDIM + col] = f2bf(acc[qt][dc][r] * inv);
      }
    }
  }
}

extern "C" void kernel_launch(void* const* d_in, const int* in_sizes, int n_in,
                              void* d_out, int out_size, void* d_ws, size_t ws_size,
                              hipStream_t stream) {
  const float* x   = (const float*)d_in[0];
  const int* mask  = (const int*)d_in[1];
  const float* lng = (const float*)d_in[2];
  const float* lnb = (const float*)d_in[3];
  const float* wq  = (const float*)d_in[4];
  const float* bq  = (const float*)d_in[5];
  const float* wk  = (const float*)d_in[6];
  const float* bk  = (const float*)d_in[7];
  const float* wv  = (const float*)d_in[8];
  const float* bv  = (const float*)d_in[9];
  const float* wo  = (const float*)d_in[10];
  const float* bo  = (const float*)d_in[11];
  float* out = (float*)d_out;
  char* ws = (char*)d_ws;

  unsigned short* h   = (unsigned short*)ws;                       // 16MB (B*T*H bf16)
  unsigned short* wbf = (unsigned short*)(ws + (16u << 20));       // 8MB (4 weights bf16)
  unsigned short* qs  = (unsigned short*)(ws + (24u << 20));       // 16MB
  unsigned short* ks  = (unsigned short*)(ws + (40u << 20));       // 16MB
  unsigned short* vs  = (unsigned short*)(ws + (56u << 20));       // 16MB
  unsigned short* c   = h;  // h dead after QKV GEMM

  convert_w<<<4096, 256, 0, stream>>>(wq, wk, wv, wo, wbf);
  ln_kernel<<<BATCH * TSEQ, 256, 0, stream>>>(x, lng, lnb, h);
  gemm_k<0><<<dim3(8, 64, 3), 256, 0, stream>>>(h, wbf, bq, bk, bv, qs, ks, vs, nullptr, nullptr);
  attn_kernel<<<dim3(TSEQ / 128, NH, BATCH), 256, 0, stream>>>(qs, ks, vs, mask, c);
  gemm_k<1><<<dim3(8, 64, 1), 256, 0, stream>>>(c, wbf + (size_t)3 * HDIM * HDIM, bo, nullptr, nullptr,
                                                nullptr, nullptr, nullptr, x, out);
}